// Round 1
// baseline (285.007 us; speedup 1.0000x reference)
//
#include <hip/hip_runtime.h>

#define TW 64
#define TH 64
#define HALO 3
#define SW (TW + 2 * HALO)   // 70
#define SH (TH + 2 * HALO)   // 70

__device__ __forceinline__ int reflect_idx(int i, int n) {
    // jnp.pad mode="reflect": border not repeated. halo(3) << n(1024), one fold suffices.
    if (i < 0) i = -i;
    if (i >= n) i = 2 * n - 2 - i;
    return i;
}

__global__ __launch_bounds__(256) void boxblur_kernel(const float* __restrict__ in,
                                                      float* __restrict__ out,
                                                      int H, int W) {
    __shared__ float s_in[SH][SW];     // 70x70 input patch
    __shared__ float s_h[SH][TW];      // horizontal 7-sum, 70x64

    const int tid = threadIdx.x;
    const int img = blockIdx.z;                 // N*C plane
    const int ty0 = blockIdx.y * TH;
    const int tx0 = blockIdx.x * TW;

    const float* __restrict__ src = in + (size_t)img * H * W;
    float* __restrict__ dst = out + (size_t)img * H * W;

    // ---- stage input patch (with reflect at borders) ----
    for (int i = tid; i < SH * SW; i += 256) {
        int r = i / SW;
        int c = i - r * SW;
        int gy = reflect_idx(ty0 - HALO + r, H);
        int gx = reflect_idx(tx0 - HALO + c, W);
        s_in[r][c] = src[(size_t)gy * W + gx];
    }
    __syncthreads();

    // ---- horizontal 7-tap sum: s_h[r][c] = sum_{j=0..6} s_in[r][c+j] ----
    for (int i = tid; i < SH * TW; i += 256) {
        int r = i / TW;
        int c = i - r * TW;
        float s = 0.0f;
#pragma unroll
        for (int j = 0; j < 7; ++j) s += s_in[r][c + j];
        s_h[r][c] = s;
    }
    __syncthreads();

    // ---- vertical 7-tap sum, normalize, store (coalesced: c contiguous) ----
    const float inv = 1.0f / 49.0f;
    for (int i = tid; i < TH * TW; i += 256) {
        int r = i / TW;
        int c = i - r * TW;
        float s = 0.0f;
#pragma unroll
        for (int j = 0; j < 7; ++j) s += s_h[r + j][c];
        dst[(size_t)(ty0 + r) * W + (tx0 + c)] = s * inv;
    }
}

extern "C" void kernel_launch(void* const* d_in, const int* in_sizes, int n_in,
                              void* d_out, int out_size, void* d_ws, size_t ws_size,
                              hipStream_t stream) {
    const float* x = (const float*)d_in[0];
    float* out = (float*)d_out;
    const int H = 1024, W = 1024;
    const int NC = 32 * 3;
    dim3 grid(W / TW, H / TH, NC);   // 16 x 16 x 96
    dim3 block(256);
    boxblur_kernel<<<grid, block, 0, stream>>>(x, out, H, W);
}

// Round 2
// 252.983 us; speedup vs baseline: 1.1266x; 1.1266x over previous
//
#include <hip/hip_runtime.h>

#define TW 64
#define TH 64
#define SW 72        // staged columns: gx in [tx0-4, tx0+68)  (16B-aligned start)
#define SH 70        // staged rows:    gy in [ty0-3, ty0+67)
#define SW4 (SW / 4) // 18 float4 per staged row

__device__ __forceinline__ int reflect_idx(int i, int n) {
    // jnp.pad mode="reflect" (border not repeated); halo << n so one fold suffices.
    if (i < 0) i = -i;
    if (i >= n) i = 2 * n - 2 - i;
    return i;
}

__global__ __launch_bounds__(256) void boxblur_kernel(const float* __restrict__ in,
                                                      float* __restrict__ out,
                                                      int H, int W) {
    __shared__ float s_in[SH][SW];   // 70x72 staged patch   (20,160 B)
    __shared__ float s_h[SH][TW];    // 70x64 horizontal sums (17,920 B)

    const int tid = threadIdx.x;
    const int img = blockIdx.z;                  // N*C plane
    const int ty0 = blockIdx.y * TH;
    const int tx0 = blockIdx.x * TW;

    const float* __restrict__ src = in + (size_t)img * H * W;
    float* __restrict__ dst = out + (size_t)img * H * W;

    const bool interior_x = (tx0 >= 4) && (tx0 + TW + 4 <= W);

    // ---- stage input patch ----
    if (interior_x) {
        const int gx0 = tx0 - 4;                 // multiple of 4 -> 16B aligned
        for (int i = tid; i < SH * SW4; i += 256) {   // 1260 float4
            int r = i / SW4;
            int c4 = i - r * SW4;
            int gy = reflect_idx(ty0 - 3 + r, H);
            float4 v = *reinterpret_cast<const float4*>(&src[(size_t)gy * W + gx0 + 4 * c4]);
            *reinterpret_cast<float4*>(&s_in[r][4 * c4]) = v;
        }
    } else {
        // x-edge blocks (2 of 16 per row): scalar staging with x-reflection
        for (int i = tid; i < SH * SW; i += 256) {
            int r = i / SW;
            int c = i - r * SW;
            int gy = reflect_idx(ty0 - 3 + r, H);
            int gx = reflect_idx(tx0 - 4 + c, W);
            s_in[r][c] = src[(size_t)gy * W + gx];
        }
    }
    __syncthreads();

    // ---- horizontal 7-tap sums (sliding window over 12 staged floats -> 4 outputs) ----
    // output col c taps patch cols c+1 .. c+7
    for (int i = tid; i < SH * (TW / 4); i += 256) {  // 70*16 = 1120 float4
        int r = i >> 4;
        int c4 = i & 15;
        float4 v0 = *reinterpret_cast<const float4*>(&s_in[r][4 * c4]);
        float4 v1 = *reinterpret_cast<const float4*>(&s_in[r][4 * c4 + 4]);
        float4 v2 = *reinterpret_cast<const float4*>(&s_in[r][4 * c4 + 8]);
        float a1 = v0.y, a2 = v0.z, a3 = v0.w;
        float a4 = v1.x, a5 = v1.y, a6 = v1.z, a7 = v1.w;
        float a8 = v2.x, a9 = v2.y, a10 = v2.z;
        float o0 = a1 + a2 + a3 + a4 + a5 + a6 + a7;
        float o1 = o0 - a1 + a8;
        float o2 = o1 - a2 + a9;
        float o3 = o2 - a3 + a10;
        *reinterpret_cast<float4*>(&s_h[r][4 * c4]) = make_float4(o0, o1, o2, o3);
    }
    __syncthreads();

    // ---- vertical 7-tap sum + normalize + coalesced float4 store ----
    const float inv = 1.0f / 49.0f;
    for (int i = tid; i < TH * (TW / 4); i += 256) {  // 64*16 = 1024 float4
        int r = i >> 4;
        int c4 = i & 15;
        float4 s = *reinterpret_cast<const float4*>(&s_h[r][4 * c4]);
#pragma unroll
        for (int j = 1; j < 7; ++j) {
            float4 v = *reinterpret_cast<const float4*>(&s_h[r + j][4 * c4]);
            s.x += v.x; s.y += v.y; s.z += v.z; s.w += v.w;
        }
        *reinterpret_cast<float4*>(&dst[(size_t)(ty0 + r) * W + tx0 + 4 * c4]) =
            make_float4(s.x * inv, s.y * inv, s.z * inv, s.w * inv);
    }
}

extern "C" void kernel_launch(void* const* d_in, const int* in_sizes, int n_in,
                              void* d_out, int out_size, void* d_ws, size_t ws_size,
                              hipStream_t stream) {
    const float* x = (const float*)d_in[0];
    float* out = (float*)d_out;
    const int H = 1024, W = 1024;
    const int NC = 32 * 3;
    dim3 grid(W / TW, H / TH, NC);   // 16 x 16 x 96
    dim3 block(256);
    boxblur_kernel<<<grid, block, 0, stream>>>(x, out, H, W);
}